// Round 1
// baseline (14146.126 us; speedup 1.0000x reference)
//
#include <hip/hip_runtime.h>
#include <hip/hip_bf16.h>
#include <math.h>

// WaveNet autoregressive generation, MI355X fp32 vector kernel.
// Decomposition: one workgroup (256 threads) per batch element (B=128).
// Each WG runs the full T-step autoregressive loop; batch elements are
// independent so no grid sync is needed. fp32 throughout: argmax feedback
// means bf16/MFMA would diverge trajectories (no fp32 MFMA on CDNA4).

#define NL 30      // layers
#define NC 64      // residual channels
#define NS 256     // skip channels
#define NV 256     // vocab
#define NB 128     // batch
#define QTOT 3069  // sum of dilations: 3 * (1+2+...+512)

// Dilation queues: 128 batch * 3069 slots * 64 ch * 4B = ~100.5 MB.
// Static device memory (d_ws size unknown). Slots are written at step t and
// read at step t+d; reads are gated by (t >= d) so no init is required and
// no stale state from a previous launch is ever observed.
__device__ float g_queues[(size_t)NB * QTOT * NC];

__global__ __launch_bounds__(256, 1)
void wavenet_gen_kernel(const int* __restrict__ seed,
                        const float* __restrict__ emb,     // (V, C)
                        const float* __restrict__ kern,    // (L, 2, C, 2C)
                        const float* __restrict__ cbias,   // (L, 2C)
                        const float* __restrict__ resw,    // (L, C, C)
                        const float* __restrict__ resb,    // (L, C)
                        const float* __restrict__ skipw,   // (L, C, S)
                        const float* __restrict__ skipb,   // (L, S)
                        const float* __restrict__ w0,      // (S, V)
                        const float* __restrict__ b0,      // (V)
                        const float* __restrict__ w1,      // (V, V)
                        const float* __restrict__ b1,      // (V)
                        const int* __restrict__ pT,
                        float* __restrict__ out)
{
  const int b = blockIdx.x;
  const int tid = threadIdx.x;
  const int T = pT[0];  // max_infer_samples (128)

  __shared__ float sx[NC];          // current residual vector x
  __shared__ float sxl[NC];         // x_last popped from dilation queue
  __shared__ float shp[2][2 * NC];  // conv partial sums (K0-half, K1-half)
  __shared__ float sg[NC];          // gated activation
  __shared__ float sskip[NS];       // skip (for the output matmul)
  __shared__ float sh0[NV];         // hidden of output head
  __shared__ float rv[4];           // per-wave argmax partials
  __shared__ int   ri[4];
  __shared__ int   snext;

  // x = embedding[seed[b]]
  if (tid < NC) sx[tid] = emb[(size_t)seed[b] * NC + tid];
  __syncthreads();

  float* __restrict__ q = g_queues + (size_t)b * QTOT * NC;
  const size_t logits_base = (size_t)NB * (size_t)T;  // samples block first

  for (int t = 0; t < T; ++t) {
    float skipacc = 0.f;  // per-thread private skip accumulator (one col each)
    int qoff = 0;

    for (int i = 0; i < NL; ++i) {
      const int d = 1 << (i % 10);

      // --- dilation queue: pop x_last, push current x (circular buffer) ---
      if (tid < NC) {
        const int slot = t & (d - 1);
        float* qs = q + (size_t)(qoff + slot) * NC + tid;
        sxl[tid] = (t >= d) ? *qs : 0.f;  // zeros before the queue fills
        *qs = sx[tid];
      }
      __syncthreads();

      // --- causal conv (k=2): h = x_last @ K0 + x @ K1 + bias ---
      // 256 threads: j = tid&127 output col, half = tid>>7 selects K0/K1 dot.
      {
        const int j = tid & 127;
        const int half = tid >> 7;
        const float* __restrict__ W =
            kern + ((size_t)(i * 2 + half)) * NC * 2 * NC + j;
        const float* __restrict__ xv = half ? sx : sxl;
        float acc = 0.f;
#pragma unroll
        for (int c = 0; c < NC; ++c) acc = fmaf(xv[c], W[(size_t)c * 2 * NC], acc);
        shp[half][j] = acc;
      }
      __syncthreads();

      // --- gated activation: g = tanh(h[:C]) * sigmoid(h[C:]) ---
      if (tid < NC) {
        const float ha = shp[0][tid] + shp[1][tid] + cbias[i * 2 * NC + tid];
        const float hb = shp[0][tid + NC] + shp[1][tid + NC] + cbias[i * 2 * NC + NC + tid];
        sg[tid] = tanhf(ha) * (1.f / (1.f + expf(-hb)));
      }
      __syncthreads();

      // --- skip: 256 threads, one output column each, 64-deep dot ---
      {
        const float* __restrict__ SW = skipw + (size_t)i * NC * NS + tid;
        float acc = 0.f;
#pragma unroll
        for (int c = 0; c < NC; ++c) acc = fmaf(sg[c], SW[(size_t)c * NS], acc);
        skipacc += acc + skipb[i * NS + tid];
      }
      // --- residual: x = x + g @ res_w + res_b (threads 0..63) ---
      if (tid < NC) {
        const float* __restrict__ RW = resw + (size_t)i * NC * NC + tid;
        float acc = 0.f;
#pragma unroll
        for (int c = 0; c < NC; ++c) acc = fmaf(sg[c], RW[(size_t)c * NC], acc);
        sx[tid] = sx[tid] + acc + resb[i * NC + tid];
      }
      qoff += d;
      __syncthreads();
    }

    // --- output head ---
    sskip[tid] = fmaxf(skipacc, 0.f);  // relu(skip)
    __syncthreads();
    {
      const float* __restrict__ W = w0 + tid;
      float acc = 0.f;
#pragma unroll 8
      for (int s = 0; s < NS; ++s) acc = fmaf(sskip[s], W[(size_t)s * NV], acc);
      sh0[tid] = fmaxf(acc + b0[tid], 0.f);  // relu(skip @ w0 + b0)
    }
    __syncthreads();
    float lg;
    {
      const float* __restrict__ W = w1 + tid;
      float acc = 0.f;
#pragma unroll 8
      for (int s = 0; s < NV; ++s) acc = fmaf(sh0[s], W[(size_t)s * NV], acc);
      lg = acc + b1[tid];
      out[logits_base + ((size_t)b * T + t) * NV + tid] = lg;
    }

    // --- argmax over 256 logits, first-max-index semantics (match jnp) ---
    float v = lg;
    int ix = tid;
#pragma unroll
    for (int o = 32; o > 0; o >>= 1) {
      float ov = __shfl_down(v, o);
      int oi = __shfl_down(ix, o);
      if (ov > v || (ov == v && oi < ix)) { v = ov; ix = oi; }
    }
    if ((tid & 63) == 0) { rv[tid >> 6] = v; ri[tid >> 6] = ix; }
    __syncthreads();
    if (tid == 0) {
      float bv = rv[0];
      int bi = ri[0];
#pragma unroll
      for (int w = 1; w < 4; ++w)
        if (rv[w] > bv || (rv[w] == bv && ri[w] < bi)) { bv = rv[w]; bi = ri[w]; }
      snext = bi;
      out[(size_t)b * T + t] = (float)bi;  // samples written as float
    }
    __syncthreads();

    // --- feedback: x = embedding[argmax] ---
    if (tid < NC) sx[tid] = emb[(size_t)snext * NC + tid];
    __syncthreads();
  }
}

extern "C" void kernel_launch(void* const* d_in, const int* in_sizes, int n_in,
                              void* d_out, int out_size, void* d_ws, size_t ws_size,
                              hipStream_t stream) {
  (void)in_sizes; (void)n_in; (void)out_size; (void)d_ws; (void)ws_size;
  wavenet_gen_kernel<<<NB, 256, 0, stream>>>(
      (const int*)d_in[0],   (const float*)d_in[1], (const float*)d_in[2],
      (const float*)d_in[3], (const float*)d_in[4], (const float*)d_in[5],
      (const float*)d_in[6], (const float*)d_in[7], (const float*)d_in[8],
      (const float*)d_in[9], (const float*)d_in[10], (const float*)d_in[11],
      (const int*)d_in[12],  (float*)d_out);
}